// Round 1
// baseline (714.012 us; speedup 1.0000x reference)
//
#include <hip/hip_runtime.h>
#include <math.h>

#define N_NODES 50000
#define N_EDGES 800000
#define IN_DIM  9
#define HIDDEN  256
#define N_CAND  4096

// ---------------- CSR build ----------------

__global__ void hist_kernel(const int* __restrict__ dst, int* __restrict__ cnt) {
    int e = blockIdx.x * blockDim.x + threadIdx.x;
    if (e < N_EDGES) atomicAdd(&cnt[dst[e]], 1);
}

__global__ __launch_bounds__(1024) void scan_kernel(const int* __restrict__ cnt,
                                                    int* __restrict__ row_ptr,
                                                    float* __restrict__ dinv) {
    __shared__ int sdata[1024];
    const int t = threadIdx.x;
    const int CHUNK = (N_NODES + 1023) / 1024;  // 49
    int beg = t * CHUNK;
    int end = beg + CHUNK; if (end > N_NODES) end = N_NODES;
    if (beg > N_NODES) beg = N_NODES;
    int sum = 0;
    for (int i = beg; i < end; ++i) sum += cnt[i];
    sdata[t] = sum;
    __syncthreads();
    // Hillis-Steele inclusive scan over 1024 partials
    for (int off = 1; off < 1024; off <<= 1) {
        int v = (t >= off) ? sdata[t - off] : 0;
        __syncthreads();
        sdata[t] += v;
        __syncthreads();
    }
    int run = sdata[t] - sum;  // exclusive prefix of this thread's chunk
    for (int i = beg; i < end; ++i) {
        int c = cnt[i];
        row_ptr[i] = run;
        run += c;
        // degree includes the self-loop: deg = in-degree + 1  (always > 0)
        dinv[i] = 1.0f / sqrtf((float)(c + 1));
    }
    if (t == 1023) row_ptr[N_NODES] = sdata[1023];
}

__global__ void fill_kernel(const int* __restrict__ srcv, const int* __restrict__ dstv,
                            const int* __restrict__ row_ptr, int* __restrict__ cur,
                            int* __restrict__ col) {
    int e = blockIdx.x * blockDim.x + threadIdx.x;
    if (e < N_EDGES) {
        int d = dstv[e];
        int pos = row_ptr[d] + atomicAdd(&cur[d], 1);
        col[pos] = srcv[e];
    }
}

// ---------------- Layer 1 dense part: m = x @ W1 ----------------

__global__ __launch_bounds__(256) void gemm1_kernel(const float* __restrict__ x,
                                                    const float* __restrict__ W1,
                                                    float* __restrict__ m) {
    int node = blockIdx.x;
    int c = threadIdx.x;
    __shared__ float xs[IN_DIM];
    if (c < IN_DIM) xs[c] = x[node * IN_DIM + c];
    __syncthreads();
    float acc = 0.f;
#pragma unroll
    for (int k = 0; k < IN_DIM; ++k) acc += xs[k] * W1[k * HIDDEN + c];
    m[(size_t)node * HIDDEN + c] = acc;
}

// ---------------- Aggregation: h = relu(dinv_i*(dinv_i*m_i + sum dinv_s*m_s) + b) ----
// one wave (64 lanes) per node, float4 per lane = 256 cols

__global__ __launch_bounds__(256) void agg_kernel(const float* __restrict__ m,
                                                  const float* __restrict__ bias,
                                                  const int* __restrict__ row_ptr,
                                                  const int* __restrict__ col,
                                                  const float* __restrict__ dinv,
                                                  float* __restrict__ hout) {
    int node = blockIdx.x * 4 + (threadIdx.x >> 6);
    if (node >= N_NODES) return;
    int lane = threadIdx.x & 63;
    const float di = dinv[node];
    float4 v = ((const float4*)(m + (size_t)node * HIDDEN))[lane];
    float4 acc = make_float4(di * v.x, di * v.y, di * v.z, di * v.w);
    int j = row_ptr[node], end = row_ptr[node + 1];
    for (; j < end; ++j) {
        int s = col[j];
        float w = dinv[s];
        float4 mv = ((const float4*)(m + (size_t)s * HIDDEN))[lane];
        acc.x += w * mv.x; acc.y += w * mv.y; acc.z += w * mv.z; acc.w += w * mv.w;
    }
    float4 b = ((const float4*)bias)[lane];
    float4 o;
    o.x = fmaxf(di * acc.x + b.x, 0.f);
    o.y = fmaxf(di * acc.y + b.y, 0.f);
    o.z = fmaxf(di * acc.z + b.z, 0.f);
    o.w = fmaxf(di * acc.w + b.w, 0.f);
    ((float4*)(hout + (size_t)node * HIDDEN))[lane] = o;
}

// ---------------- Layer 2 dense part: C = H @ W2  (fp32 tiled GEMM) ----------------
// 128x128 tile, BK=16, 256 threads, 8x8 per-thread register block

#define BM 128
#define BN 128
#define BK 16

__global__ __launch_bounds__(256) void gemm2_kernel(const float* __restrict__ A,
                                                    const float* __restrict__ B,
                                                    float* __restrict__ C, int M) {
    __shared__ float As[BK][BM + 4];  // +4 pad keeps rows 16B-aligned for b128 reads
    __shared__ float Bs[BK][BN];
    const int row0 = blockIdx.x * BM;
    const int col0 = blockIdx.y * BN;
    const int tid = threadIdx.x;
    const int tx = tid & 15;   // 0..15 -> col block of 8
    const int ty = tid >> 4;   // 0..15 -> row block of 8

    float acc[8][8];
#pragma unroll
    for (int i = 0; i < 8; ++i)
#pragma unroll
        for (int j = 0; j < 8; ++j) acc[i][j] = 0.f;

    const int arow = tid >> 1;          // 0..127
    const int ak = (tid & 1) * 8;       // 0 or 8
    const int bk = tid >> 4;            // 0..15
    const int bn = (tid & 15) * 8;      // 0..120

    for (int k0 = 0; k0 < HIDDEN; k0 += BK) {
        // load A tile (transposed into LDS)
        int garow = row0 + arow;
        float4 a0, a1;
        if (garow < M) {
            a0 = *(const float4*)(A + (size_t)garow * HIDDEN + k0 + ak);
            a1 = *(const float4*)(A + (size_t)garow * HIDDEN + k0 + ak + 4);
        } else {
            a0 = make_float4(0, 0, 0, 0);
            a1 = make_float4(0, 0, 0, 0);
        }
        As[ak + 0][arow] = a0.x; As[ak + 1][arow] = a0.y;
        As[ak + 2][arow] = a0.z; As[ak + 3][arow] = a0.w;
        As[ak + 4][arow] = a1.x; As[ak + 5][arow] = a1.y;
        As[ak + 6][arow] = a1.z; As[ak + 7][arow] = a1.w;
        // load B tile (direct)
        *(float4*)(&Bs[bk][bn])     = *(const float4*)(B + (size_t)(k0 + bk) * HIDDEN + col0 + bn);
        *(float4*)(&Bs[bk][bn + 4]) = *(const float4*)(B + (size_t)(k0 + bk) * HIDDEN + col0 + bn + 4);
        __syncthreads();

#pragma unroll
        for (int k = 0; k < BK; ++k) {
            float a[8], b[8];
#pragma unroll
            for (int i = 0; i < 8; ++i) a[i] = As[k][ty * 8 + i];
#pragma unroll
            for (int j = 0; j < 8; ++j) b[j] = Bs[k][tx * 8 + j];
#pragma unroll
            for (int i = 0; i < 8; ++i)
#pragma unroll
                for (int j = 0; j < 8; ++j) acc[i][j] += a[i] * b[j];
        }
        __syncthreads();
    }

#pragma unroll
    for (int i = 0; i < 8; ++i) {
        int gr = row0 + ty * 8 + i;
        if (gr < M) {
            float4 v0 = make_float4(acc[i][0], acc[i][1], acc[i][2], acc[i][3]);
            float4 v1 = make_float4(acc[i][4], acc[i][5], acc[i][6], acc[i][7]);
            *(float4*)(C + (size_t)gr * HIDDEN + col0 + tx * 8)     = v0;
            *(float4*)(C + (size_t)gr * HIDDEN + col0 + tx * 8 + 4) = v1;
        }
    }
}

// ---------------- Score head ----------------

__global__ __launch_bounds__(256) void head_kernel(const float* __restrict__ h,
                                                   const int* __restrict__ cand,
                                                   const float* __restrict__ Wh1,
                                                   const float* __restrict__ bh1,
                                                   const float* __restrict__ Wh2,
                                                   const float* __restrict__ bh2,
                                                   float* __restrict__ out) {
    int k = blockIdx.x;
    int c = threadIdx.x;
    __shared__ float row[HIDDEN];
    __shared__ float red[4];
    int node = cand[k];
    row[c] = h[(size_t)node * HIDDEN + c];
    __syncthreads();
    float acc = bh1[c];
#pragma unroll 8
    for (int i = 0; i < HIDDEN; ++i) acc += row[i] * Wh1[i * HIDDEN + c];
    float t = tanhf(acc);
    float p = t * Wh2[c];
    // wave (64-lane) reduction
#pragma unroll
    for (int off = 32; off > 0; off >>= 1) p += __shfl_down(p, off);
    if ((c & 63) == 0) red[c >> 6] = p;
    __syncthreads();
    if (c == 0) out[k] = red[0] + red[1] + red[2] + red[3] + bh2[0];
}

// ---------------- launch ----------------

extern "C" void kernel_launch(void* const* d_in, const int* in_sizes, int n_in,
                              void* d_out, int out_size, void* d_ws, size_t ws_size,
                              hipStream_t stream) {
    const float* x   = (const float*)d_in[0];
    const float* W1  = (const float*)d_in[1];
    const float* b1  = (const float*)d_in[2];
    const float* W2  = (const float*)d_in[3];
    const float* b2  = (const float*)d_in[4];
    const float* Wh1 = (const float*)d_in[5];
    const float* bh1 = (const float*)d_in[6];
    const float* Wh2 = (const float*)d_in[7];
    const float* bh2 = (const float*)d_in[8];
    const int* edge_index = (const int*)d_in[9];   // [2, E]: src then dst
    const int* cand       = (const int*)d_in[10];
    float* out = (float*)d_out;

    char* ws = (char*)d_ws;
    size_t off = 0;
    auto alloc = [&](size_t bytes) -> void* {
        void* p = ws + off;
        off += (bytes + 255) & ~(size_t)255;
        return p;
    };
    int*   cnt     = (int*)alloc((size_t)N_NODES * 4);
    int*   row_ptr = (int*)alloc((size_t)(N_NODES + 1) * 4);
    int*   cur     = (int*)alloc((size_t)N_NODES * 4);
    float* dinv    = (float*)alloc((size_t)N_NODES * 4);
    int*   col     = (int*)alloc((size_t)N_EDGES * 4);
    float* bufA    = (float*)alloc((size_t)N_NODES * HIDDEN * 4);
    float* bufB    = (float*)alloc((size_t)N_NODES * HIDDEN * 4);

    const int* src = edge_index;
    const int* dst = edge_index + N_EDGES;

    hipMemsetAsync(cnt, 0, (size_t)N_NODES * 4, stream);
    hipMemsetAsync(cur, 0, (size_t)N_NODES * 4, stream);

    const int EB = (N_EDGES + 255) / 256;
    hist_kernel<<<EB, 256, 0, stream>>>(dst, cnt);
    scan_kernel<<<1, 1024, 0, stream>>>(cnt, row_ptr, dinv);
    fill_kernel<<<EB, 256, 0, stream>>>(src, dst, row_ptr, cur, col);

    gemm1_kernel<<<N_NODES, 256, 0, stream>>>(x, W1, bufA);
    agg_kernel<<<(N_NODES + 3) / 4, 256, 0, stream>>>(bufA, b1, row_ptr, col, dinv, bufB);
    gemm2_kernel<<<dim3((N_NODES + BM - 1) / BM, HIDDEN / BN), 256, 0, stream>>>(bufB, W2, bufA, N_NODES);
    agg_kernel<<<(N_NODES + 3) / 4, 256, 0, stream>>>(bufA, b2, row_ptr, col, dinv, bufB);
    head_kernel<<<N_CAND, 256, 0, stream>>>(bufB, cand, Wh1, bh1, Wh2, bh2, out);
}

// Round 5
// 358.749 us; speedup vs baseline: 1.9903x; 1.9903x over previous
//
#include <hip/hip_runtime.h>
#include <math.h>

#define N_NODES 50000
#define N_EDGES 800000
#define IN_DIM  9
#define HIDDEN  256
#define N_CAND  4096

// ---------------- CSR build ----------------

__global__ void hist_kernel(const int* __restrict__ dst, int* __restrict__ cnt) {
    int e = blockIdx.x * blockDim.x + threadIdx.x;
    if (e < N_EDGES) atomicAdd(&cnt[dst[e]], 1);
}

__global__ __launch_bounds__(1024) void scan_kernel(const int* __restrict__ cnt,
                                                    int* __restrict__ row_ptr,
                                                    float* __restrict__ dinv) {
    __shared__ int sdata[1024];
    const int t = threadIdx.x;
    const int CHUNK = (N_NODES + 1023) / 1024;  // 49
    int beg = t * CHUNK;
    int end = beg + CHUNK; if (end > N_NODES) end = N_NODES;
    if (beg > N_NODES) beg = N_NODES;
    int sum = 0;
    for (int i = beg; i < end; ++i) sum += cnt[i];
    sdata[t] = sum;
    __syncthreads();
    for (int off = 1; off < 1024; off <<= 1) {
        int v = (t >= off) ? sdata[t - off] : 0;
        __syncthreads();
        sdata[t] += v;
        __syncthreads();
    }
    int run = sdata[t] - sum;
    for (int i = beg; i < end; ++i) {
        int c = cnt[i];
        row_ptr[i] = run;
        run += c;
        dinv[i] = 1.0f / sqrtf((float)(c + 1));  // deg includes self-loop
    }
    if (t == 1023) row_ptr[N_NODES] = sdata[1023];
}

__global__ void fill_kernel(const int* __restrict__ srcv, const int* __restrict__ dstv,
                            const int* __restrict__ row_ptr, int* __restrict__ cur,
                            int* __restrict__ col) {
    int e = blockIdx.x * blockDim.x + threadIdx.x;
    if (e < N_EDGES) {
        int d = dstv[e];
        int pos = row_ptr[d] + atomicAdd(&cur[d], 1);
        col[pos] = srcv[e];
    }
}

// ---------------- Layer-1 aggregation on RAW 9-dim features ----------------
// Agg(x)[i] = dinv_i*(dinv_i*x_i + sum_s dinv_s*x_s); x is 1.8MB -> L2-resident.
// One thread per node.

__global__ __launch_bounds__(256) void aggx_kernel(const float* __restrict__ x,
                                                   const int* __restrict__ row_ptr,
                                                   const int* __restrict__ col,
                                                   const float* __restrict__ dinv,
                                                   float* __restrict__ ax) {
    int i = blockIdx.x * blockDim.x + threadIdx.x;
    if (i >= N_NODES) return;
    float di = dinv[i];
    float a[IN_DIM];
    const float* xi = x + (size_t)i * IN_DIM;
#pragma unroll
    for (int d = 0; d < IN_DIM; ++d) a[d] = di * xi[d];
    int j = row_ptr[i], end = row_ptr[i + 1];
    for (; j < end; ++j) {
        int s = col[j];
        float w = dinv[s];
        const float* xs = x + (size_t)s * IN_DIM;
#pragma unroll
        for (int d = 0; d < IN_DIM; ++d) a[d] += w * xs[d];
    }
    float* o = ax + (size_t)i * IN_DIM;
#pragma unroll
    for (int d = 0; d < IN_DIM; ++d) o[d] = di * a[d];
}

// ---------------- h1 = relu(ax @ W1 + b1), all nodes ----------------
// 8 nodes per 256-thread block; thread = output column.

#define NPB 8
__global__ __launch_bounds__(256) void h1_kernel(const float* __restrict__ ax,
                                                 const float* __restrict__ W1,
                                                 const float* __restrict__ b1,
                                                 float* __restrict__ h1) {
    int n0 = blockIdx.x * NPB;
    int c = threadIdx.x;
    __shared__ float s[NPB][IN_DIM];
    if (c < NPB * IN_DIM) s[c / IN_DIM][c % IN_DIM] = ax[(size_t)n0 * IN_DIM + c];
    __syncthreads();
    float w[IN_DIM];
#pragma unroll
    for (int k = 0; k < IN_DIM; ++k) w[k] = W1[k * HIDDEN + c];
    float b = b1[c];
#pragma unroll
    for (int r = 0; r < NPB; ++r) {
        float acc = b;
#pragma unroll
        for (int k = 0; k < IN_DIM; ++k) acc += s[r][k] * w[k];
        h1[(size_t)(n0 + r) * HIDDEN + c] = fmaxf(acc, 0.f);
    }
}

// ---------------- Candidate-only aggregation of h1: g[k] = Agg(h1)[cand[k]] ----
// one wave per candidate, float4 per lane = 256 cols

__global__ __launch_bounds__(256) void aggc_kernel(const float* __restrict__ h1,
                                                   const int* __restrict__ cand,
                                                   const int* __restrict__ row_ptr,
                                                   const int* __restrict__ col,
                                                   const float* __restrict__ dinv,
                                                   float* __restrict__ g) {
    int k = blockIdx.x * 4 + (threadIdx.x >> 6);
    if (k >= N_CAND) return;
    int lane = threadIdx.x & 63;
    int node = cand[k];
    const float di = dinv[node];
    float4 v = ((const float4*)(h1 + (size_t)node * HIDDEN))[lane];
    float4 acc = make_float4(di * v.x, di * v.y, di * v.z, di * v.w);
    int j = row_ptr[node], end = row_ptr[node + 1];
    for (; j < end; ++j) {
        int s = col[j];
        float w = dinv[s];
        float4 mv = ((const float4*)(h1 + (size_t)s * HIDDEN))[lane];
        acc.x += w * mv.x; acc.y += w * mv.y; acc.z += w * mv.z; acc.w += w * mv.w;
    }
    float4 o = make_float4(di * acc.x, di * acc.y, di * acc.z, di * acc.w);
    ((float4*)(g + (size_t)k * HIDDEN))[lane] = o;
}

// ---------------- Fused candidate head ----------------
// h2 = relu(g@W2+b2); t = tanh(h2@Wh1+bh1); out = t@Wh2+bh2
// 16 candidates per 256-thread block; thread = output column.

#define CPB 16
__global__ __launch_bounds__(256) void head_fused_kernel(const float* __restrict__ g,
                                                         const float* __restrict__ W2,
                                                         const float* __restrict__ b2,
                                                         const float* __restrict__ Wh1,
                                                         const float* __restrict__ bh1,
                                                         const float* __restrict__ Wh2,
                                                         const float* __restrict__ bh2,
                                                         float* __restrict__ out) {
    __shared__ float A[CPB][HIDDEN];
    __shared__ float B[CPB][HIDDEN];
    __shared__ float red[CPB][4];
    int k0 = blockIdx.x * CPB;
    int c = threadIdx.x;

#pragma unroll
    for (int r = 0; r < CPB; ++r) A[r][c] = g[(size_t)(k0 + r) * HIDDEN + c];
    __syncthreads();

    // stage 1: h2 = relu(A @ W2 + b2)
    float acc[CPB];
    {
        float b = b2[c];
#pragma unroll
        for (int r = 0; r < CPB; ++r) acc[r] = b;
        for (int i = 0; i < HIDDEN; i += 4) {
            float w0 = W2[(i + 0) * HIDDEN + c];
            float w1 = W2[(i + 1) * HIDDEN + c];
            float w2 = W2[(i + 2) * HIDDEN + c];
            float w3 = W2[(i + 3) * HIDDEN + c];
#pragma unroll
            for (int r = 0; r < CPB; ++r) {
                float4 a = *(const float4*)&A[r][i];
                acc[r] += a.x * w0 + a.y * w1 + a.z * w2 + a.w * w3;
            }
        }
#pragma unroll
        for (int r = 0; r < CPB; ++r) B[r][c] = fmaxf(acc[r], 0.f);
    }
    __syncthreads();

    // stage 2: t = tanh(B @ Wh1 + bh1); p = t * Wh2[c]
    {
        float b = bh1[c];
#pragma unroll
        for (int r = 0; r < CPB; ++r) acc[r] = b;
        for (int i = 0; i < HIDDEN; i += 4) {
            float w0 = Wh1[(i + 0) * HIDDEN + c];
            float w1 = Wh1[(i + 1) * HIDDEN + c];
            float w2 = Wh1[(i + 2) * HIDDEN + c];
            float w3 = Wh1[(i + 3) * HIDDEN + c];
#pragma unroll
            for (int r = 0; r < CPB; ++r) {
                float4 a = *(const float4*)&B[r][i];
                acc[r] += a.x * w0 + a.y * w1 + a.z * w2 + a.w * w3;
            }
        }
        float w2c = Wh2[c];
#pragma unroll
        for (int r = 0; r < CPB; ++r) acc[r] = tanhf(acc[r]) * w2c;
    }

    // per-row reduction over 256 threads (4 waves)
#pragma unroll
    for (int r = 0; r < CPB; ++r) {
        float v = acc[r];
#pragma unroll
        for (int off = 32; off > 0; off >>= 1) v += __shfl_down(v, off);
        if ((c & 63) == 0) red[r][c >> 6] = v;
    }
    __syncthreads();
    if (c < CPB) out[k0 + c] = red[c][0] + red[c][1] + red[c][2] + red[c][3] + bh2[0];
}

// ---------------- launch ----------------

extern "C" void kernel_launch(void* const* d_in, const int* in_sizes, int n_in,
                              void* d_out, int out_size, void* d_ws, size_t ws_size,
                              hipStream_t stream) {
    const float* x   = (const float*)d_in[0];
    const float* W1  = (const float*)d_in[1];
    const float* b1  = (const float*)d_in[2];
    const float* W2  = (const float*)d_in[3];
    const float* b2  = (const float*)d_in[4];
    const float* Wh1 = (const float*)d_in[5];
    const float* bh1 = (const float*)d_in[6];
    const float* Wh2 = (const float*)d_in[7];
    const float* bh2 = (const float*)d_in[8];
    const int* edge_index = (const int*)d_in[9];   // [2, E]: src then dst
    const int* cand       = (const int*)d_in[10];
    float* out = (float*)d_out;

    char* ws = (char*)d_ws;
    size_t off = 0;
    auto alloc = [&](size_t bytes) -> void* {
        void* p = ws + off;
        off += (bytes + 255) & ~(size_t)255;
        return p;
    };
    int*   cnt     = (int*)alloc((size_t)N_NODES * 4);
    int*   row_ptr = (int*)alloc((size_t)(N_NODES + 1) * 4);
    int*   cur     = (int*)alloc((size_t)N_NODES * 4);
    float* dinv    = (float*)alloc((size_t)N_NODES * 4);
    int*   col     = (int*)alloc((size_t)N_EDGES * 4);
    float* ax      = (float*)alloc((size_t)N_NODES * IN_DIM * 4);
    float* h1      = (float*)alloc((size_t)N_NODES * HIDDEN * 4);
    float* g       = (float*)alloc((size_t)N_CAND * HIDDEN * 4);

    const int* src = edge_index;
    const int* dst = edge_index + N_EDGES;

    hipMemsetAsync(cnt, 0, (size_t)N_NODES * 4, stream);
    hipMemsetAsync(cur, 0, (size_t)N_NODES * 4, stream);

    const int EB = (N_EDGES + 255) / 256;
    hist_kernel<<<EB, 256, 0, stream>>>(dst, cnt);
    scan_kernel<<<1, 1024, 0, stream>>>(cnt, row_ptr, dinv);
    fill_kernel<<<EB, 256, 0, stream>>>(src, dst, row_ptr, cur, col);

    aggx_kernel<<<(N_NODES + 255) / 256, 256, 0, stream>>>(x, row_ptr, col, dinv, ax);
    h1_kernel<<<N_NODES / NPB, 256, 0, stream>>>(ax, W1, b1, h1);
    aggc_kernel<<<(N_CAND + 3) / 4, 256, 0, stream>>>(h1, cand, row_ptr, col, dinv, g);
    head_fused_kernel<<<N_CAND / CPB, 256, 0, stream>>>(g, W2, b2, Wh1, bh1, Wh2, bh2, out);
}

// Round 7
// 258.355 us; speedup vs baseline: 2.7637x; 1.3886x over previous
//
#include <hip/hip_runtime.h>
#include <math.h>

#define N_NODES 50000
#define N_EDGES 800000
#define IN_DIM  9
#define HIDDEN  256
#define N_CAND  4096

#define SCAN_TPB 256
#define SCAN_NB  ((N_NODES + SCAN_TPB - 1) / SCAN_TPB)   // 196

// ---------------- CSR build ----------------

__global__ void hist_kernel(const int* __restrict__ dst, int* __restrict__ cnt) {
    int e = blockIdx.x * blockDim.x + threadIdx.x;
    if (e < N_EDGES) atomicAdd(&cnt[dst[e]], 1);
}

// Phase 1: block-local exclusive scan of cnt -> row_ptr (within-block prefix),
// block totals -> blockSums
__global__ __launch_bounds__(SCAN_TPB) void scan1_kernel(const int* __restrict__ cnt,
                                                         int* __restrict__ row_ptr,
                                                         int* __restrict__ blockSums) {
    __shared__ int s[SCAN_TPB];
    int t = threadIdx.x;
    int i = blockIdx.x * SCAN_TPB + t;
    int v = (i < N_NODES) ? cnt[i] : 0;
    s[t] = v;
    __syncthreads();
#pragma unroll
    for (int off = 1; off < SCAN_TPB; off <<= 1) {
        int u = (t >= off) ? s[t - off] : 0;
        __syncthreads();
        s[t] += u;
        __syncthreads();
    }
    if (i < N_NODES) row_ptr[i] = s[t] - v;          // exclusive within block
    if (t == SCAN_TPB - 1) blockSums[blockIdx.x] = s[t];  // block total
}

// Phase 2: single block scans the block totals (exclusive) -> blockOff;
// also writes row_ptr[N_NODES] = grand total
__global__ __launch_bounds__(SCAN_TPB) void scan2_kernel(const int* __restrict__ blockSums,
                                                         int* __restrict__ blockOff,
                                                         int* __restrict__ row_ptr) {
    __shared__ int s[SCAN_TPB];
    int t = threadIdx.x;
    int v = (t < SCAN_NB) ? blockSums[t] : 0;
    s[t] = v;
    __syncthreads();
#pragma unroll
    for (int off = 1; off < SCAN_TPB; off <<= 1) {
        int u = (t >= off) ? s[t - off] : 0;
        __syncthreads();
        s[t] += u;
        __syncthreads();
    }
    if (t < SCAN_NB) blockOff[t] = s[t] - v;
    if (t == SCAN_TPB - 1) row_ptr[N_NODES] = s[t];
}

// Phase 3: add block offsets; compute dinv (deg includes self-loop)
__global__ __launch_bounds__(SCAN_TPB) void scan3_kernel(const int* __restrict__ cnt,
                                                         const int* __restrict__ blockOff,
                                                         int* __restrict__ row_ptr,
                                                         float* __restrict__ dinv) {
    int i = blockIdx.x * SCAN_TPB + threadIdx.x;
    if (i < N_NODES) {
        row_ptr[i] += blockOff[blockIdx.x];
        dinv[i] = 1.0f / sqrtf((float)(cnt[i] + 1));
    }
}

__global__ void fill_kernel(const int* __restrict__ srcv, const int* __restrict__ dstv,
                            const int* __restrict__ row_ptr, int* __restrict__ cur,
                            int* __restrict__ col) {
    int e = blockIdx.x * blockDim.x + threadIdx.x;
    if (e < N_EDGES) {
        int d = dstv[e];
        int pos = row_ptr[d] + atomicAdd(&cur[d], 1);
        col[pos] = srcv[e];
    }
}

// ---------------- Layer-1 aggregation on RAW 9-dim features ----------------
// Agg(x)[i] = dinv_i*(dinv_i*x_i + sum_s dinv_s*x_s); x is 1.8MB -> L2-resident.
// One thread per node.

__global__ __launch_bounds__(256) void aggx_kernel(const float* __restrict__ x,
                                                   const int* __restrict__ row_ptr,
                                                   const int* __restrict__ col,
                                                   const float* __restrict__ dinv,
                                                   float* __restrict__ ax) {
    int i = blockIdx.x * blockDim.x + threadIdx.x;
    if (i >= N_NODES) return;
    float di = dinv[i];
    float a[IN_DIM];
    const float* xi = x + (size_t)i * IN_DIM;
#pragma unroll
    for (int d = 0; d < IN_DIM; ++d) a[d] = di * xi[d];
    int j = row_ptr[i], end = row_ptr[i + 1];
    for (; j < end; ++j) {
        int s = col[j];
        float w = dinv[s];
        const float* xs = x + (size_t)s * IN_DIM;
#pragma unroll
        for (int d = 0; d < IN_DIM; ++d) a[d] += w * xs[d];
    }
    float* o = ax + (size_t)i * IN_DIM;
#pragma unroll
    for (int d = 0; d < IN_DIM; ++d) o[d] = di * a[d];
}

// ---------------- h1 = relu(ax @ W1 + b1), all nodes ----------------
// 8 nodes per 256-thread block; thread = output column.

#define NPB 8
__global__ __launch_bounds__(256) void h1_kernel(const float* __restrict__ ax,
                                                 const float* __restrict__ W1,
                                                 const float* __restrict__ b1,
                                                 float* __restrict__ h1) {
    int n0 = blockIdx.x * NPB;
    int c = threadIdx.x;
    __shared__ float s[NPB][IN_DIM];
    if (c < NPB * IN_DIM) s[c / IN_DIM][c % IN_DIM] = ax[(size_t)n0 * IN_DIM + c];
    __syncthreads();
    float w[IN_DIM];
#pragma unroll
    for (int k = 0; k < IN_DIM; ++k) w[k] = W1[k * HIDDEN + c];
    float b = b1[c];
#pragma unroll
    for (int r = 0; r < NPB; ++r) {
        float acc = b;
#pragma unroll
        for (int k = 0; k < IN_DIM; ++k) acc += s[r][k] * w[k];
        h1[(size_t)(n0 + r) * HIDDEN + c] = fmaxf(acc, 0.f);
    }
}

// ---------------- Candidate-only aggregation of h1: g[k] = Agg(h1)[cand[k]] ----
// one wave per candidate, float4 per lane = 256 cols

__global__ __launch_bounds__(256) void aggc_kernel(const float* __restrict__ h1,
                                                   const int* __restrict__ cand,
                                                   const int* __restrict__ row_ptr,
                                                   const int* __restrict__ col,
                                                   const float* __restrict__ dinv,
                                                   float* __restrict__ g) {
    int k = blockIdx.x * 4 + (threadIdx.x >> 6);
    if (k >= N_CAND) return;
    int lane = threadIdx.x & 63;
    int node = cand[k];
    const float di = dinv[node];
    float4 v = ((const float4*)(h1 + (size_t)node * HIDDEN))[lane];
    float4 acc = make_float4(di * v.x, di * v.y, di * v.z, di * v.w);
    int j = row_ptr[node], end = row_ptr[node + 1];
    for (; j < end; ++j) {
        int s = col[j];
        float w = dinv[s];
        float4 mv = ((const float4*)(h1 + (size_t)s * HIDDEN))[lane];
        acc.x += w * mv.x; acc.y += w * mv.y; acc.z += w * mv.z; acc.w += w * mv.w;
    }
    float4 o = make_float4(di * acc.x, di * acc.y, di * acc.z, di * acc.w);
    ((float4*)(g + (size_t)k * HIDDEN))[lane] = o;
}

// ---------------- Fused candidate head ----------------
// h2 = relu(g@W2+b2); t = tanh(h2@Wh1+bh1); out = t@Wh2+bh2
// 16 candidates per 256-thread block; thread = output column.

#define CPB 16
__global__ __launch_bounds__(256) void head_fused_kernel(const float* __restrict__ g,
                                                         const float* __restrict__ W2,
                                                         const float* __restrict__ b2,
                                                         const float* __restrict__ Wh1,
                                                         const float* __restrict__ bh1,
                                                         const float* __restrict__ Wh2,
                                                         const float* __restrict__ bh2,
                                                         float* __restrict__ out) {
    __shared__ float A[CPB][HIDDEN];
    __shared__ float B[CPB][HIDDEN];
    __shared__ float red[CPB][4];
    int k0 = blockIdx.x * CPB;
    int c = threadIdx.x;

#pragma unroll
    for (int r = 0; r < CPB; ++r) A[r][c] = g[(size_t)(k0 + r) * HIDDEN + c];
    __syncthreads();

    // stage 1: h2 = relu(A @ W2 + b2)
    float acc[CPB];
    {
        float b = b2[c];
#pragma unroll
        for (int r = 0; r < CPB; ++r) acc[r] = b;
        for (int i = 0; i < HIDDEN; i += 4) {
            float w0 = W2[(i + 0) * HIDDEN + c];
            float w1 = W2[(i + 1) * HIDDEN + c];
            float w2 = W2[(i + 2) * HIDDEN + c];
            float w3 = W2[(i + 3) * HIDDEN + c];
#pragma unroll
            for (int r = 0; r < CPB; ++r) {
                float4 a = *(const float4*)&A[r][i];
                acc[r] += a.x * w0 + a.y * w1 + a.z * w2 + a.w * w3;
            }
        }
#pragma unroll
        for (int r = 0; r < CPB; ++r) B[r][c] = fmaxf(acc[r], 0.f);
    }
    __syncthreads();

    // stage 2: t = tanh(B @ Wh1 + bh1); p = t * Wh2[c]
    {
        float b = bh1[c];
#pragma unroll
        for (int r = 0; r < CPB; ++r) acc[r] = b;
        for (int i = 0; i < HIDDEN; i += 4) {
            float w0 = Wh1[(i + 0) * HIDDEN + c];
            float w1 = Wh1[(i + 1) * HIDDEN + c];
            float w2 = Wh1[(i + 2) * HIDDEN + c];
            float w3 = Wh1[(i + 3) * HIDDEN + c];
#pragma unroll
            for (int r = 0; r < CPB; ++r) {
                float4 a = *(const float4*)&B[r][i];
                acc[r] += a.x * w0 + a.y * w1 + a.z * w2 + a.w * w3;
            }
        }
        float w2c = Wh2[c];
#pragma unroll
        for (int r = 0; r < CPB; ++r) acc[r] = tanhf(acc[r]) * w2c;
    }

    // per-row reduction over 256 threads (4 waves)
#pragma unroll
    for (int r = 0; r < CPB; ++r) {
        float v = acc[r];
#pragma unroll
        for (int off = 32; off > 0; off >>= 1) v += __shfl_down(v, off);
        if ((c & 63) == 0) red[r][c >> 6] = v;
    }
    __syncthreads();
    if (c < CPB) out[k0 + c] = red[c][0] + red[c][1] + red[c][2] + red[c][3] + bh2[0];
}

// ---------------- launch ----------------

extern "C" void kernel_launch(void* const* d_in, const int* in_sizes, int n_in,
                              void* d_out, int out_size, void* d_ws, size_t ws_size,
                              hipStream_t stream) {
    const float* x   = (const float*)d_in[0];
    const float* W1  = (const float*)d_in[1];
    const float* b1  = (const float*)d_in[2];
    const float* W2  = (const float*)d_in[3];
    const float* b2  = (const float*)d_in[4];
    const float* Wh1 = (const float*)d_in[5];
    const float* bh1 = (const float*)d_in[6];
    const float* Wh2 = (const float*)d_in[7];
    const float* bh2 = (const float*)d_in[8];
    const int* edge_index = (const int*)d_in[9];   // [2, E]: src then dst
    const int* cand       = (const int*)d_in[10];
    float* out = (float*)d_out;

    char* ws = (char*)d_ws;
    size_t off = 0;
    auto alloc = [&](size_t bytes) -> void* {
        void* p = ws + off;
        off += (bytes + 255) & ~(size_t)255;
        return p;
    };
    int*   cnt       = (int*)alloc((size_t)N_NODES * 4);
    int*   row_ptr   = (int*)alloc((size_t)(N_NODES + 1) * 4);
    int*   cur       = (int*)alloc((size_t)N_NODES * 4);
    float* dinv      = (float*)alloc((size_t)N_NODES * 4);
    int*   blockSums = (int*)alloc((size_t)SCAN_NB * 4);
    int*   blockOff  = (int*)alloc((size_t)SCAN_NB * 4);
    int*   col       = (int*)alloc((size_t)N_EDGES * 4);
    float* ax        = (float*)alloc((size_t)N_NODES * IN_DIM * 4);
    float* h1        = (float*)alloc((size_t)N_NODES * HIDDEN * 4);
    float* g         = (float*)alloc((size_t)N_CAND * HIDDEN * 4);

    const int* src = edge_index;
    const int* dst = edge_index + N_EDGES;

    hipMemsetAsync(cnt, 0, (size_t)N_NODES * 4, stream);
    hipMemsetAsync(cur, 0, (size_t)N_NODES * 4, stream);

    const int EB = (N_EDGES + 255) / 256;
    hist_kernel<<<EB, 256, 0, stream>>>(dst, cnt);
    scan1_kernel<<<SCAN_NB, SCAN_TPB, 0, stream>>>(cnt, row_ptr, blockSums);
    scan2_kernel<<<1, SCAN_TPB, 0, stream>>>(blockSums, blockOff, row_ptr);
    scan3_kernel<<<SCAN_NB, SCAN_TPB, 0, stream>>>(cnt, blockOff, row_ptr, dinv);
    fill_kernel<<<EB, 256, 0, stream>>>(src, dst, row_ptr, cur, col);

    aggx_kernel<<<(N_NODES + 255) / 256, 256, 0, stream>>>(x, row_ptr, col, dinv, ax);
    h1_kernel<<<N_NODES / NPB, 256, 0, stream>>>(ax, W1, b1, h1);
    aggc_kernel<<<(N_CAND + 3) / 4, 256, 0, stream>>>(h1, cand, row_ptr, col, dinv, g);
    head_fused_kernel<<<N_CAND / CPB, 256, 0, stream>>>(g, W2, b2, Wh1, bh1, Wh2, bh2, out);
}

// Round 8
// 242.378 us; speedup vs baseline: 2.9459x; 1.0659x over previous
//
#include <hip/hip_runtime.h>
#include <math.h>

#define N_NODES 50000
#define N_EDGES 800000
#define IN_DIM  9
#define HIDDEN  256
#define N_CAND  4096

#define SCAN_TPB 256
#define SCAN_NB  ((N_NODES + SCAN_TPB - 1) / SCAN_TPB)   // 196

// ---------------- CSR build ----------------

__global__ void hist_kernel(const int* __restrict__ dst, int* __restrict__ cnt) {
    int e = blockIdx.x * blockDim.x + threadIdx.x;
    if (e < N_EDGES) atomicAdd(&cnt[dst[e]], 1);
}

// Phase 1: block-local exclusive scan of cnt -> row_ptr (within-block prefix),
// block totals -> blockSums
__global__ __launch_bounds__(SCAN_TPB) void scan1_kernel(const int* __restrict__ cnt,
                                                         int* __restrict__ row_ptr,
                                                         int* __restrict__ blockSums) {
    __shared__ int s[SCAN_TPB];
    int t = threadIdx.x;
    int i = blockIdx.x * SCAN_TPB + t;
    int v = (i < N_NODES) ? cnt[i] : 0;
    s[t] = v;
    __syncthreads();
#pragma unroll
    for (int off = 1; off < SCAN_TPB; off <<= 1) {
        int u = (t >= off) ? s[t - off] : 0;
        __syncthreads();
        s[t] += u;
        __syncthreads();
    }
    if (i < N_NODES) row_ptr[i] = s[t] - v;          // exclusive within block
    if (t == SCAN_TPB - 1) blockSums[blockIdx.x] = s[t];  // block total
}

// Phase 2: single block scans the block totals (exclusive) -> blockOff;
// also writes row_ptr[N_NODES] = grand total
__global__ __launch_bounds__(SCAN_TPB) void scan2_kernel(const int* __restrict__ blockSums,
                                                         int* __restrict__ blockOff,
                                                         int* __restrict__ row_ptr) {
    __shared__ int s[SCAN_TPB];
    int t = threadIdx.x;
    int v = (t < SCAN_NB) ? blockSums[t] : 0;
    s[t] = v;
    __syncthreads();
#pragma unroll
    for (int off = 1; off < SCAN_TPB; off <<= 1) {
        int u = (t >= off) ? s[t - off] : 0;
        __syncthreads();
        s[t] += u;
        __syncthreads();
    }
    if (t < SCAN_NB) blockOff[t] = s[t] - v;
    if (t == SCAN_TPB - 1) row_ptr[N_NODES] = s[t];
}

// Phase 3: add block offsets; compute dinv (deg includes self-loop)
__global__ __launch_bounds__(SCAN_TPB) void scan3_kernel(const int* __restrict__ cnt,
                                                         const int* __restrict__ blockOff,
                                                         int* __restrict__ row_ptr,
                                                         float* __restrict__ dinv) {
    int i = blockIdx.x * SCAN_TPB + threadIdx.x;
    if (i < N_NODES) {
        row_ptr[i] += blockOff[blockIdx.x];
        dinv[i] = 1.0f / sqrtf((float)(cnt[i] + 1));
    }
}

__global__ void fill_kernel(const int* __restrict__ srcv, const int* __restrict__ dstv,
                            const int* __restrict__ row_ptr, int* __restrict__ cur,
                            int* __restrict__ col) {
    int e = blockIdx.x * blockDim.x + threadIdx.x;
    if (e < N_EDGES) {
        int d = dstv[e];
        int pos = row_ptr[d] + atomicAdd(&cur[d], 1);
        col[pos] = srcv[e];
    }
}

// ---------------- Layer-1 aggregation on RAW 9-dim features ----------------
// Agg(x)[i] = dinv_i*(dinv_i*x_i + sum_s dinv_s*x_s); x is 1.8MB -> L2-resident.
// One thread per node.

__global__ __launch_bounds__(256) void aggx_kernel(const float* __restrict__ x,
                                                   const int* __restrict__ row_ptr,
                                                   const int* __restrict__ col,
                                                   const float* __restrict__ dinv,
                                                   float* __restrict__ ax) {
    int i = blockIdx.x * blockDim.x + threadIdx.x;
    if (i >= N_NODES) return;
    float di = dinv[i];
    float a[IN_DIM];
    const float* xi = x + (size_t)i * IN_DIM;
#pragma unroll
    for (int d = 0; d < IN_DIM; ++d) a[d] = di * xi[d];
    int j = row_ptr[i], end = row_ptr[i + 1];
    for (; j < end; ++j) {
        int s = col[j];
        float w = dinv[s];
        const float* xs = x + (size_t)s * IN_DIM;
#pragma unroll
        for (int d = 0; d < IN_DIM; ++d) a[d] += w * xs[d];
    }
    float* o = ax + (size_t)i * IN_DIM;
#pragma unroll
    for (int d = 0; d < IN_DIM; ++d) o[d] = di * a[d];
}

// ---------------- h1 = relu(ax @ W1 + b1), all nodes ----------------
// 8 nodes per 256-thread block; thread = output column.

#define NPB 8
__global__ __launch_bounds__(256) void h1_kernel(const float* __restrict__ ax,
                                                 const float* __restrict__ W1,
                                                 const float* __restrict__ b1,
                                                 float* __restrict__ h1) {
    int n0 = blockIdx.x * NPB;
    int c = threadIdx.x;
    __shared__ float s[NPB][IN_DIM];
    if (c < NPB * IN_DIM) s[c / IN_DIM][c % IN_DIM] = ax[(size_t)n0 * IN_DIM + c];
    __syncthreads();
    float w[IN_DIM];
#pragma unroll
    for (int k = 0; k < IN_DIM; ++k) w[k] = W1[k * HIDDEN + c];
    float b = b1[c];
#pragma unroll
    for (int r = 0; r < NPB; ++r) {
        float acc = b;
#pragma unroll
        for (int k = 0; k < IN_DIM; ++k) acc += s[r][k] * w[k];
        h1[(size_t)(n0 + r) * HIDDEN + c] = fmaxf(acc, 0.f);
    }
}

// ---------------- Candidate-only aggregation of h1: g[k] = Agg(h1)[cand[k]] ----
// one wave per candidate, float4 per lane = 256 cols

__global__ __launch_bounds__(256) void aggc_kernel(const float* __restrict__ h1,
                                                   const int* __restrict__ cand,
                                                   const int* __restrict__ row_ptr,
                                                   const int* __restrict__ col,
                                                   const float* __restrict__ dinv,
                                                   float* __restrict__ g) {
    int k = blockIdx.x * 4 + (threadIdx.x >> 6);
    if (k >= N_CAND) return;
    int lane = threadIdx.x & 63;
    int node = cand[k];
    const float di = dinv[node];
    float4 v = ((const float4*)(h1 + (size_t)node * HIDDEN))[lane];
    float4 acc = make_float4(di * v.x, di * v.y, di * v.z, di * v.w);
    int j = row_ptr[node], end = row_ptr[node + 1];
    for (; j < end; ++j) {
        int s = col[j];
        float w = dinv[s];
        float4 mv = ((const float4*)(h1 + (size_t)s * HIDDEN))[lane];
        acc.x += w * mv.x; acc.y += w * mv.y; acc.z += w * mv.z; acc.w += w * mv.w;
    }
    float4 o = make_float4(di * acc.x, di * acc.y, di * acc.z, di * acc.w);
    ((float4*)(g + (size_t)k * HIDDEN))[lane] = o;
}

// ---------------- Fused candidate head ----------------
// h2 = relu(g@W2+b2); t = tanh(h2@Wh1+bh1); out = t@Wh2+bh2
// CPB candidates per 256-thread block; thread = output column.
// CPB=4: grid 1024 blocks -> 4 blocks/CU -> 4 waves/SIMD (was CPB=16: 1 wave/SIMD,
// latency-bound at VALUBusy 28%, occupancy 10%).

#define CPB 4
__global__ __launch_bounds__(256) void head_fused_kernel(const float* __restrict__ g,
                                                         const float* __restrict__ W2,
                                                         const float* __restrict__ b2,
                                                         const float* __restrict__ Wh1,
                                                         const float* __restrict__ bh1,
                                                         const float* __restrict__ Wh2,
                                                         const float* __restrict__ bh2,
                                                         float* __restrict__ out) {
    __shared__ float A[CPB][HIDDEN];
    __shared__ float B[CPB][HIDDEN];
    __shared__ float red[CPB][4];
    int k0 = blockIdx.x * CPB;
    int c = threadIdx.x;

#pragma unroll
    for (int r = 0; r < CPB; ++r) A[r][c] = g[(size_t)(k0 + r) * HIDDEN + c];
    __syncthreads();

    // stage 1: h2 = relu(A @ W2 + b2)
    float acc[CPB];
    {
        float b = b2[c];
#pragma unroll
        for (int r = 0; r < CPB; ++r) acc[r] = b;
        for (int i = 0; i < HIDDEN; i += 4) {
            float w0 = W2[(i + 0) * HIDDEN + c];
            float w1 = W2[(i + 1) * HIDDEN + c];
            float w2 = W2[(i + 2) * HIDDEN + c];
            float w3 = W2[(i + 3) * HIDDEN + c];
#pragma unroll
            for (int r = 0; r < CPB; ++r) {
                float4 a = *(const float4*)&A[r][i];
                acc[r] += a.x * w0 + a.y * w1 + a.z * w2 + a.w * w3;
            }
        }
#pragma unroll
        for (int r = 0; r < CPB; ++r) B[r][c] = fmaxf(acc[r], 0.f);
    }
    __syncthreads();

    // stage 2: t = tanh(B @ Wh1 + bh1); p = t * Wh2[c]
    {
        float b = bh1[c];
#pragma unroll
        for (int r = 0; r < CPB; ++r) acc[r] = b;
        for (int i = 0; i < HIDDEN; i += 4) {
            float w0 = Wh1[(i + 0) * HIDDEN + c];
            float w1 = Wh1[(i + 1) * HIDDEN + c];
            float w2 = Wh1[(i + 2) * HIDDEN + c];
            float w3 = Wh1[(i + 3) * HIDDEN + c];
#pragma unroll
            for (int r = 0; r < CPB; ++r) {
                float4 a = *(const float4*)&B[r][i];
                acc[r] += a.x * w0 + a.y * w1 + a.z * w2 + a.w * w3;
            }
        }
        float w2c = Wh2[c];
#pragma unroll
        for (int r = 0; r < CPB; ++r) acc[r] = tanhf(acc[r]) * w2c;
    }

    // per-row reduction over 256 threads (4 waves)
#pragma unroll
    for (int r = 0; r < CPB; ++r) {
        float v = acc[r];
#pragma unroll
        for (int off = 32; off > 0; off >>= 1) v += __shfl_down(v, off);
        if ((c & 63) == 0) red[r][c >> 6] = v;
    }
    __syncthreads();
    if (c < CPB) out[k0 + c] = red[c][0] + red[c][1] + red[c][2] + red[c][3] + bh2[0];
}

// ---------------- launch ----------------

extern "C" void kernel_launch(void* const* d_in, const int* in_sizes, int n_in,
                              void* d_out, int out_size, void* d_ws, size_t ws_size,
                              hipStream_t stream) {
    const float* x   = (const float*)d_in[0];
    const float* W1  = (const float*)d_in[1];
    const float* b1  = (const float*)d_in[2];
    const float* W2  = (const float*)d_in[3];
    const float* b2  = (const float*)d_in[4];
    const float* Wh1 = (const float*)d_in[5];
    const float* bh1 = (const float*)d_in[6];
    const float* Wh2 = (const float*)d_in[7];
    const float* bh2 = (const float*)d_in[8];
    const int* edge_index = (const int*)d_in[9];   // [2, E]: src then dst
    const int* cand       = (const int*)d_in[10];
    float* out = (float*)d_out;

    char* ws = (char*)d_ws;
    size_t off = 0;
    auto alloc = [&](size_t bytes) -> void* {
        void* p = ws + off;
        off += (bytes + 255) & ~(size_t)255;
        return p;
    };
    int*   cnt       = (int*)alloc((size_t)N_NODES * 4);
    int*   row_ptr   = (int*)alloc((size_t)(N_NODES + 1) * 4);
    int*   cur       = (int*)alloc((size_t)N_NODES * 4);
    float* dinv      = (float*)alloc((size_t)N_NODES * 4);
    int*   blockSums = (int*)alloc((size_t)SCAN_NB * 4);
    int*   blockOff  = (int*)alloc((size_t)SCAN_NB * 4);
    int*   col       = (int*)alloc((size_t)N_EDGES * 4);
    float* ax        = (float*)alloc((size_t)N_NODES * IN_DIM * 4);
    float* h1        = (float*)alloc((size_t)N_NODES * HIDDEN * 4);
    float* g         = (float*)alloc((size_t)N_CAND * HIDDEN * 4);

    const int* src = edge_index;
    const int* dst = edge_index + N_EDGES;

    hipMemsetAsync(cnt, 0, (size_t)N_NODES * 4, stream);
    hipMemsetAsync(cur, 0, (size_t)N_NODES * 4, stream);

    const int EB = (N_EDGES + 255) / 256;
    hist_kernel<<<EB, 256, 0, stream>>>(dst, cnt);
    scan1_kernel<<<SCAN_NB, SCAN_TPB, 0, stream>>>(cnt, row_ptr, blockSums);
    scan2_kernel<<<1, SCAN_TPB, 0, stream>>>(blockSums, blockOff, row_ptr);
    scan3_kernel<<<SCAN_NB, SCAN_TPB, 0, stream>>>(cnt, blockOff, row_ptr, dinv);
    fill_kernel<<<EB, 256, 0, stream>>>(src, dst, row_ptr, cur, col);

    aggx_kernel<<<(N_NODES + 255) / 256, 256, 0, stream>>>(x, row_ptr, col, dinv, ax);
    h1_kernel<<<N_NODES / NPB, 256, 0, stream>>>(ax, W1, b1, h1);
    aggc_kernel<<<(N_CAND + 3) / 4, 256, 0, stream>>>(h1, cand, row_ptr, col, dinv, g);
    head_fused_kernel<<<N_CAND / CPB, 256, 0, stream>>>(g, W2, b2, Wh1, bh1, Wh2, bh2, out);
}